// Round 15
// baseline (570.844 us; speedup 1.0000x reference)
//
#include <hip/hip_runtime.h>
#include <math.h>

#define F_IN 128
#define HID  64
#define EPS  1e-5f
#define NSLOPE 0.2f
#define BSH 9            // bucket = 512 consecutive dst nodes
#define MAXBUK 1024      // supports N <= 512K
#define EPB 4096         // edges per block in bucket passes
#define SPB 4096         // elements per block in scan

__device__ __forceinline__ float lrelu(float x) { return x > 0.f ? x : NSLOPE * x; }

// bf16 pack/unpack (RNE). Gather targets are stored bf16 to halve L2-miss bytes.
__device__ __forceinline__ unsigned short f2bf(float f) {
  unsigned u = __float_as_uint(f);
  return (unsigned short)((u + 0x7FFF + ((u >> 16) & 1)) >> 16);
}
__device__ __forceinline__ float bf2f(unsigned short b) {
  return __uint_as_float((unsigned)b << 16);
}

// ================================================================ CSR build
__global__ __launch_bounds__(256) void k_buk_count(const int* __restrict__ ei,
                                                   int* __restrict__ bukcnt, int E, int nbuk) {
  __shared__ int lc[MAXBUK];
  for (int k = threadIdx.x; k < nbuk; k += 256) lc[k] = 0;
  __syncthreads();
  int base = blockIdx.x * EPB, end = min(E, base + EPB);
  for (int t = base + threadIdx.x; t < end; t += 256) atomicAdd(&lc[ei[E + t] >> BSH], 1);
  __syncthreads();
  for (int k = threadIdx.x; k < nbuk; k += 256)
    if (lc[k]) atomicAdd(&bukcnt[k], lc[k]);
}

__global__ void k_buk_scan(const int* __restrict__ bukcnt, int* __restrict__ bukbase, int nbuk) {
  __shared__ int l[MAXBUK + 1];
  for (int k = threadIdx.x; k < nbuk; k += blockDim.x) l[k] = bukcnt[k];
  __syncthreads();
  if (threadIdx.x == 0) {
    int r = 0;
    for (int k = 0; k < nbuk; ++k) { int t = l[k]; l[k] = r; r += t; }
    l[nbuk] = r;
  }
  __syncthreads();
  for (int k = threadIdx.x; k <= nbuk; k += blockDim.x) bukbase[k] = l[k];
}

__global__ __launch_bounds__(256) void k_buk_scatter(const int* __restrict__ ei,
                                                     const int* __restrict__ bukbase,
                                                     int* __restrict__ bukcur,
                                                     int2* __restrict__ pairs, int E, int nbuk) {
  __shared__ int lc[MAXBUK];
  __shared__ int lbase[MAXBUK];
  for (int k = threadIdx.x; k < nbuk; k += 256) lc[k] = 0;
  __syncthreads();
  int base = blockIdx.x * EPB, end = min(E, base + EPB);
  for (int t = base + threadIdx.x; t < end; t += 256) atomicAdd(&lc[ei[E + t] >> BSH], 1);
  __syncthreads();
  for (int k = threadIdx.x; k < nbuk; k += 256) {
    int c = lc[k];
    lbase[k] = c ? atomicAdd(&bukcur[k], c) : 0;
  }
  __syncthreads();
  for (int k = threadIdx.x; k < nbuk; k += 256) lc[k] = 0;
  __syncthreads();
  for (int t = base + threadIdx.x; t < end; t += 256) {
    int s = ei[t], d = ei[E + t];
    int b = d >> BSH;
    int o = atomicAdd(&lc[b], 1);
    pairs[bukbase[b] + lbase[b] + o] = make_int2(s, d);
  }
}

__global__ __launch_bounds__(256) void k_buk_deg(const int2* __restrict__ pairs,
                                                 const int* __restrict__ bukbase,
                                                 int* __restrict__ ideg, int N) {
  __shared__ int ldeg[1 << BSH];
  int b = blockIdx.x;
  for (int k = threadIdx.x; k < (1 << BSH); k += 256) ldeg[k] = 0;
  __syncthreads();
  int s0 = bukbase[b], s1 = bukbase[b + 1], nb = b << BSH;
  for (int t = s0 + threadIdx.x; t < s1; t += 256) atomicAdd(&ldeg[pairs[t].y - nb], 1);
  __syncthreads();
  for (int k = threadIdx.x; k < (1 << BSH); k += 256) {
    int node = nb + k;
    if (node < N) ideg[node] = ldeg[k];
  }
}

__global__ __launch_bounds__(256) void k_scan_sums(const int* __restrict__ ideg,
                                                   int* __restrict__ bsum, int N) {
  __shared__ int red[256];
  int base = blockIdx.x * SPB + threadIdx.x * 16;
  int s = 0;
#pragma unroll
  for (int j = 0; j < 16; ++j) { int i = base + j; if (i < N) s += ideg[i] + 1; }
  red[threadIdx.x] = s;
  __syncthreads();
  for (int o = 128; o; o >>= 1) {
    if (threadIdx.x < o) red[threadIdx.x] += red[threadIdx.x + o];
    __syncthreads();
  }
  if (threadIdx.x == 0) bsum[blockIdx.x] = red[0];
}

__global__ void k_scan_tops(int* __restrict__ bsum, int nb) {
  __shared__ int l[MAXBUK];
  for (int k = threadIdx.x; k < nb; k += blockDim.x) l[k] = bsum[k];
  __syncthreads();
  if (threadIdx.x == 0) {
    int r = 0;
    for (int k = 0; k < nb; ++k) { int t = l[k]; l[k] = r; r += t; }
  }
  __syncthreads();
  for (int k = threadIdx.x; k < nb; k += blockDim.x) bsum[k] = l[k];
}

__global__ __launch_bounds__(256) void k_scan_apply(const int* __restrict__ ideg,
                                                    const int* __restrict__ bsum,
                                                    int* __restrict__ rowstart,
                                                    float* __restrict__ dinv,
                                                    int* __restrict__ csr, int N) {
  __shared__ int pre[256];
  int base = blockIdx.x * SPB + threadIdx.x * 16;
  int deg[16];
  int s = 0;
#pragma unroll
  for (int j = 0; j < 16; ++j) {
    int i = base + j;
    int d = (i < N) ? ideg[i] + 1 : 0;
    deg[j] = d; s += d;
  }
  pre[threadIdx.x] = s;
  __syncthreads();
  for (int o = 1; o < 256; o <<= 1) {
    int v = (threadIdx.x >= o) ? pre[threadIdx.x - o] : 0;
    __syncthreads();
    pre[threadIdx.x] += v;
    __syncthreads();
  }
  int off = bsum[blockIdx.x] + pre[threadIdx.x] - s;
#pragma unroll
  for (int j = 0; j < 16; ++j) {
    int i = base + j;
    if (i < N) {
      rowstart[i] = off;
      dinv[i] = rsqrtf((float)deg[j]);
      csr[off] = i;               // self-loop at slot 0
      off += deg[j];
    }
  }
}

__global__ __launch_bounds__(256) void k_buk_fill(const int2* __restrict__ pairs,
                                                  const int* __restrict__ bukbase,
                                                  const int* __restrict__ rowstart,
                                                  int* __restrict__ csr) {
  __shared__ int lcur[1 << BSH];
  int b = blockIdx.x;
  for (int k = threadIdx.x; k < (1 << BSH); k += 256) lcur[k] = 0;
  __syncthreads();
  int s0 = bukbase[b], s1 = bukbase[b + 1], nb = b << BSH;
  for (int t = s0 + threadIdx.x; t < s1; t += 256) {
    int2 pr = pairs[t];
    int o = atomicAdd(&lcur[pr.y - nb], 1);
    csr[rowstart[pr.y] + 1 + o] = pr.x;
  }
}

// ------------------------------------------------- precompute LN-folded weights
__global__ void k_precomp(const float* __restrict__ w1, const float* __restrict__ ln_g,
                          const float* __restrict__ ln_b, const float* __restrict__ b1,
                          float* __restrict__ w1g, float* __restrict__ c1,
                          float* __restrict__ cb) {
  int j = threadIdx.x;  // 64 threads
  float c1v = 0.f, cbv = 0.f;
  for (int k = 0; k < F_IN; ++k) {
    float w = w1[k * HID + j];
    float wg = ln_g[k] * w;
    w1g[k * HID + j] = wg;
    c1v += wg;
    cbv += ln_b[k] * w;
  }
  c1[j] = c1v;
  cb[j] = cbv + b1[j];
}

// -------------------- Encoder: LN (folded) + GEMM1 + ReLU + GEMM2 + ReLU
// unroll 4 on the k-loops: widens the s_load prefetch window (weights are
// wave-uniform scalar loads; SMEM latency was stalling VALU at unroll 1).
__global__ __launch_bounds__(256) void k_enc(
    const float* __restrict__ x, const float* __restrict__ w1g,
    const float* __restrict__ c1, const float* __restrict__ cb,
    const float* __restrict__ w2, const float* __restrict__ b2,
    float* __restrict__ out, int N) {
  __shared__ float shl[256 * 65];
  int i = blockIdx.x * 256 + threadIdx.x;
  if (i >= N) return;
  const float4* xr = (const float4*)(x + (size_t)i * F_IN);
  float acc[HID];
#pragma unroll
  for (int j = 0; j < HID; ++j) acc[j] = 0.f;
  float s = 0.f, q = 0.f;
#pragma unroll 4
  for (int c = 0; c < F_IN / 4; ++c) {
    float4 xv = xr[c];
    s += xv.x + xv.y + xv.z + xv.w;
    q += xv.x * xv.x + xv.y * xv.y + xv.z * xv.z + xv.w * xv.w;
    const float* wr = w1g + c * 4 * HID;
#pragma unroll
    for (int e = 0; e < 4; ++e) {
      float xe = (e == 0) ? xv.x : (e == 1) ? xv.y : (e == 2) ? xv.z : xv.w;
      const float4* w4 = (const float4*)(wr + e * HID);
#pragma unroll
      for (int j4 = 0; j4 < HID / 4; ++j4) {
        float4 wv = w4[j4];
        acc[j4 * 4 + 0] += xe * wv.x;
        acc[j4 * 4 + 1] += xe * wv.y;
        acc[j4 * 4 + 2] += xe * wv.z;
        acc[j4 * 4 + 3] += xe * wv.w;
      }
    }
  }
  float mu = s * (1.f / F_IN);
  float var = q * (1.f / F_IN) - mu * mu;
  float rs = rsqrtf(var + EPS);
  int base = threadIdx.x * 65;
#pragma unroll
  for (int j = 0; j < HID; ++j)
    shl[base + j] = fmaxf(rs * (acc[j] - mu * c1[j]) + cb[j], 0.f);
  float acc2[HID];
#pragma unroll
  for (int j = 0; j < HID; ++j) acc2[j] = b2[j];
#pragma unroll 8
  for (int j = 0; j < HID; ++j) {
    float hj = shl[base + j];
    const float4* w4 = (const float4*)(w2 + j * HID);
#pragma unroll
    for (int c4 = 0; c4 < HID / 4; ++c4) {
      float4 wv = w4[c4];
      acc2[c4 * 4 + 0] += hj * wv.x;
      acc2[c4 * 4 + 1] += hj * wv.y;
      acc2[c4 * 4 + 2] += hj * wv.z;
      acc2[c4 * 4 + 3] += hj * wv.w;
    }
  }
  float4* o4 = (float4*)(out + (size_t)i * HID);
#pragma unroll
  for (int c4 = 0; c4 < HID / 4; ++c4)
    o4[c4] = make_float4(fmaxf(acc2[c4 * 4 + 0], 0.f), fmaxf(acc2[c4 * 4 + 1], 0.f),
                         fmaxf(acc2[c4 * 4 + 2], 0.f), fmaxf(acc2[c4 * 4 + 3], 0.f));
}

// -------------------- [N,64] @ [64,FOUT], thread=node, scalar weights, bf16 out.
template <int FOUT, bool GAT, bool BNIN>
__global__ __launch_bounds__(256) void k_gemm_reg(
    const float* __restrict__ x, const float* __restrict__ w,
    const float* __restrict__ stats,
    const float* __restrict__ atts, const float* __restrict__ atd,
    unsigned short* __restrict__ out, float* __restrict__ a_s, float* __restrict__ a_d, int N) {
  int i = blockIdx.x * 256 + threadIdx.x;
  if (i >= N) return;
  const float4* xr = (const float4*)(x + (size_t)i * HID);
  float acc[FOUT];
#pragma unroll
  for (int j = 0; j < FOUT; ++j) acc[j] = 0.f;
#pragma unroll 4
  for (int c = 0; c < HID / 4; ++c) {
    float4 xv = xr[c];
    if (BNIN) {
      xv.x = fmaxf(xv.x * stats[c * 4 + 0] + stats[HID + c * 4 + 0], 0.f);
      xv.y = fmaxf(xv.y * stats[c * 4 + 1] + stats[HID + c * 4 + 1], 0.f);
      xv.z = fmaxf(xv.z * stats[c * 4 + 2] + stats[HID + c * 4 + 2], 0.f);
      xv.w = fmaxf(xv.w * stats[c * 4 + 3] + stats[HID + c * 4 + 3], 0.f);
    }
    const float* wr = w + c * 4 * FOUT;
#pragma unroll
    for (int e = 0; e < 4; ++e) {
      float xe = (e == 0) ? xv.x : (e == 1) ? xv.y : (e == 2) ? xv.z : xv.w;
      const float4* w4 = (const float4*)(wr + e * FOUT);
#pragma unroll
      for (int j4 = 0; j4 < FOUT / 4; ++j4) {
        float4 wv = w4[j4];
        acc[j4 * 4 + 0] += xe * wv.x;
        acc[j4 * 4 + 1] += xe * wv.y;
        acc[j4 * 4 + 2] += xe * wv.z;
        acc[j4 * 4 + 3] += xe * wv.w;
      }
    }
  }
  unsigned short* orow = out + (size_t)i * FOUT;
#pragma unroll
  for (int j8 = 0; j8 < FOUT / 8; ++j8) {
    uint4 pk;
    pk.x = ((unsigned)f2bf(acc[j8 * 8 + 1]) << 16) | f2bf(acc[j8 * 8 + 0]);
    pk.y = ((unsigned)f2bf(acc[j8 * 8 + 3]) << 16) | f2bf(acc[j8 * 8 + 2]);
    pk.z = ((unsigned)f2bf(acc[j8 * 8 + 5]) << 16) | f2bf(acc[j8 * 8 + 4]);
    pk.w = ((unsigned)f2bf(acc[j8 * 8 + 7]) << 16) | f2bf(acc[j8 * 8 + 6]);
    *(uint4*)(orow + j8 * 8) = pk;
  }
  if (GAT) {
    float s0 = 0.f, s1 = 0.f, d0 = 0.f, d1 = 0.f;
#pragma unroll
    for (int c = 0; c < 32; ++c) { s0 += acc[c] * atts[c]; d0 += acc[c] * atd[c]; }
#pragma unroll
    for (int c = 32; c < 64; ++c) { s1 += acc[c] * atts[c]; d1 += acc[c] * atd[c]; }
    a_s[i * 2] = s0; a_s[i * 2 + 1] = s1;
    a_d[i * 2] = d0; a_d[i * 2 + 1] = d1;
  }
}

// ---------------------------------------------------- GCN pull F=64 (wave per node)
__global__ __launch_bounds__(256) void k_gcn_pull64(
    const int* __restrict__ csr, const int* __restrict__ rowstart, const int* __restrict__ ideg,
    const float* __restrict__ dinv, const unsigned short* __restrict__ xw,
    float* __restrict__ out, int N) {
  int wave = threadIdx.x >> 6, lane = threadIdx.x & 63;
  int i = blockIdx.x * 4 + wave;
  if (i >= N) return;
  int row = rowstart[i], dg = ideg[i] + 1;
  float did = dinv[i];
  float acc = 0.f;
  for (int base = 0; base < dg; base += 64) {
    int cnt = min(64, dg - base);
    int sid = (lane < cnt) ? csr[row + base + lane] : 0;
    int n = 0;
    for (; n + 4 <= cnt; n += 4) {
      int s0 = __shfl(sid, n), s1 = __shfl(sid, n + 1);
      int s2 = __shfl(sid, n + 2), s3 = __shfl(sid, n + 3);
      acc += dinv[s0] * did * bf2f(xw[s0 * 64 + lane]) + dinv[s1] * did * bf2f(xw[s1 * 64 + lane]) +
             dinv[s2] * did * bf2f(xw[s2 * 64 + lane]) + dinv[s3] * did * bf2f(xw[s3 * 64 + lane]);
    }
    for (; n < cnt; ++n) {
      int s0 = __shfl(sid, n);
      acc += dinv[s0] * did * bf2f(xw[s0 * 64 + lane]);
    }
  }
  out[i * 64 + lane] = acc;
}

// ---------------------------------------------------- GCN pull F=32 (2 nodes per wave)
__global__ __launch_bounds__(256) void k_gcn_pull32(
    const int* __restrict__ csr, const int* __restrict__ rowstart, const int* __restrict__ ideg,
    const float* __restrict__ dinv, const unsigned short* __restrict__ xw,
    float* __restrict__ out, int N) {
  int wave = threadIdx.x >> 6, lane = threadIdx.x & 63;
  int half = lane >> 5, lf = lane & 31;
  int i = (blockIdx.x * 4 + wave) * 2 + half;
  if (i >= N) return;
  int row = rowstart[i], dg = ideg[i] + 1;
  float did = dinv[i];
  float acc = 0.f;
  for (int base = 0; base < dg; base += 32) {
    int cnt = min(32, dg - base);
    int sid = (lf < cnt) ? csr[row + base + lf] : 0;
    int n = 0;
    for (; n + 2 <= cnt; n += 2) {
      int s0 = __shfl(sid, n, 32), s1 = __shfl(sid, n + 1, 32);
      acc += dinv[s0] * did * bf2f(xw[s0 * 32 + lf]) + dinv[s1] * did * bf2f(xw[s1 * 32 + lf]);
    }
    for (; n < cnt; ++n) {
      int s0 = __shfl(sid, n, 32);
      acc += dinv[s0] * did * bf2f(xw[s0 * 32 + lf]);
    }
  }
  out[i * 32 + lf] = acc;
}

// -------------------- GAT fused: online-softmax + PV, half-wave heads.
__global__ __launch_bounds__(256) void k_gat_fused(
    const int* __restrict__ csr, const int* __restrict__ rowstart, const int* __restrict__ ideg,
    const float* __restrict__ a_s, const float* __restrict__ a_d,
    const unsigned short* __restrict__ xw, float* __restrict__ out, int N) {
  int wave = threadIdx.x >> 6, lane = threadIdx.x & 63;
  int i = blockIdx.x * 4 + wave;
  if (i >= N) return;
  int h = lane >> 5, lf = lane & 31;
  int row = rowstart[i], dg = ideg[i] + 1;
  float adh = a_d[i * 2 + h];
  float m = -1e30f, z = 0.f, accA = 0.f, accB = 0.f;
  for (int base = 0; base < dg; base += 32) {
    int cnt = min(32, dg - base);
    int sid = (lf < cnt) ? csr[row + base + lf] : 0;   // lanes l and l+32 hold same sid
    float e = -1e30f;
    if (lf < cnt) e = lrelu(a_s[sid * 2 + h] + adh);
    float cm = e;
#pragma unroll
    for (int o = 16; o; o >>= 1) cm = fmaxf(cm, __shfl_xor(cm, o));
    float nm = fmaxf(m, cm);
    float r = __expf(m - nm);          // first chunk: exp(-inf)=0 zeroes z/acc
    z *= r; accA *= r; accB *= r;
    m = nm;
    float p = (lf < cnt) ? __expf(e - m) : 0.f;
    float sz = p;
#pragma unroll
    for (int o = 16; o; o >>= 1) sz += __shfl_xor(sz, o);
    z += sz;
    int hb = h << 5;
    int n = 0;
    for (; n + 2 <= cnt; n += 2) {
      int v0 = __shfl(sid, n), v1 = __shfl(sid, n + 1);
      float al0 = __shfl(p, hb + n);
      float al1 = __shfl(p, hb + n + 1);
      accA += al0 * bf2f(xw[v0 * HID + lane]);
      accB += al1 * bf2f(xw[v1 * HID + lane]);
    }
    for (; n < cnt; ++n) {
      int v0 = __shfl(sid, n);
      float al0 = __shfl(p, hb + n);
      accA += al0 * bf2f(xw[v0 * HID + lane]);
    }
  }
  out[i * HID + lane] = (accA + accB) / (z + 1e-16f);
}

// ------------------------------ BatchNorm stats: block partials, no global atomics
template <int F>
__global__ __launch_bounds__(256) void k_bn_reduce(const float* __restrict__ x,
                                                   float* __restrict__ partials, int N) {
  __shared__ float sS[F], sQ[F];
  int tid = threadIdx.x;
  int t = blockIdx.x * 256 + tid;
  int stride = gridDim.x * 256;
  int total4 = N * F / 4;
  int f0 = (t * 4) % F;
  float s0 = 0, s1 = 0, s2 = 0, s3 = 0, q0 = 0, q1 = 0, q2 = 0, q3 = 0;
  for (int c = t; c < total4; c += stride) {
    float4 v = ((const float4*)x)[c];
    s0 += v.x; q0 += v.x * v.x;
    s1 += v.y; q1 += v.y * v.y;
    s2 += v.z; q2 += v.z * v.z;
    s3 += v.w; q3 += v.w * v.w;
  }
  if (tid < F) { sS[tid] = 0.f; sQ[tid] = 0.f; }
  __syncthreads();
  atomicAdd(&sS[f0], s0);     atomicAdd(&sQ[f0], q0);
  atomicAdd(&sS[f0 + 1], s1); atomicAdd(&sQ[f0 + 1], q1);
  atomicAdd(&sS[f0 + 2], s2); atomicAdd(&sQ[f0 + 2], q2);
  atomicAdd(&sS[f0 + 3], s3); atomicAdd(&sQ[f0 + 3], q3);
  __syncthreads();
  if (tid < F) {
    partials[blockIdx.x * 2 * F + tid]     = sS[tid];
    partials[blockIdx.x * 2 * F + F + tid] = sQ[tid];
  }
}

// 1024-thread parallel finalize
template <int F>
__global__ __launch_bounds__(1024) void k_bn_finalize(
    const float* __restrict__ partials, int nblk,
    float* __restrict__ stats, const float* __restrict__ g,
    const float* __restrict__ b, int N) {
  const int TF = 2 * F;
  const int NGRP = 1024 / TF;
  __shared__ float sh[1024];
  int tid = threadIdx.x;
  int f = tid % TF;
  int grp = tid / TF;
  float s = 0.f;
  for (int k = grp; k < nblk; k += NGRP) s += partials[(size_t)k * TF + f];
  sh[tid] = s;
  __syncthreads();
  for (int off = NGRP / 2; off > 0; off >>= 1) {
    if (grp < off) sh[tid] += sh[tid + off * TF];
    __syncthreads();
  }
  if (tid < F) {
    float S = sh[tid], Q = sh[F + tid];
    float mu = S / (float)N;
    float var = Q / (float)N - mu * mu;
    float sc = rsqrtf(var + EPS) * g[tid];
    stats[tid] = sc;
    stats[F + tid] = b[tid] - mu * sc;
  }
}

// ---------------------------------------------------- prediction head (BN3 fused)
__global__ __launch_bounds__(256) void k_pred(
    const float* __restrict__ x, const float* __restrict__ stats,
    const float* __restrict__ w1, const float* __restrict__ b1,
    const float* __restrict__ w2, const float* __restrict__ b2,
    float* __restrict__ out, int N) {
  int i = blockIdx.x * 256 + threadIdx.x;
  if (i >= N) return;
  const float4* xr = (const float4*)(x + (size_t)i * 32);
  float acc[16];
#pragma unroll
  for (int j = 0; j < 16; ++j) acc[j] = b1[j];
#pragma unroll 4
  for (int c = 0; c < 8; ++c) {
    float4 xv = xr[c];
    xv.x = fmaxf(xv.x * stats[c * 4 + 0] + stats[32 + c * 4 + 0], 0.f);
    xv.y = fmaxf(xv.y * stats[c * 4 + 1] + stats[32 + c * 4 + 1], 0.f);
    xv.z = fmaxf(xv.z * stats[c * 4 + 2] + stats[32 + c * 4 + 2], 0.f);
    xv.w = fmaxf(xv.w * stats[c * 4 + 3] + stats[32 + c * 4 + 3], 0.f);
    const float* wr = w1 + c * 4 * 16;
#pragma unroll
    for (int e = 0; e < 4; ++e) {
      float xe = (e == 0) ? xv.x : (e == 1) ? xv.y : (e == 2) ? xv.z : xv.w;
      const float4* w4 = (const float4*)(wr + e * 16);
#pragma unroll
      for (int j4 = 0; j4 < 4; ++j4) {
        float4 wv = w4[j4];
        acc[j4 * 4 + 0] += xe * wv.x;
        acc[j4 * 4 + 1] += xe * wv.y;
        acc[j4 * 4 + 2] += xe * wv.z;
        acc[j4 * 4 + 3] += xe * wv.w;
      }
    }
  }
  float z = b2[0];
#pragma unroll
  for (int j = 0; j < 16; ++j) z += fmaxf(acc[j], 0.f) * w2[j];
  out[i] = 1.f / (1.f + __expf(-z));
}

// ================================================================ launch
extern "C" void kernel_launch(void* const* d_in, const int* in_sizes, int n_in,
                              void* d_out, int out_size, void* d_ws, size_t ws_size,
                              hipStream_t stream) {
  const float* x_in  = (const float*)d_in[0];
  const int*   ei    = (const int*)d_in[1];
  const float* ln_g  = (const float*)d_in[2];
  const float* ln_b  = (const float*)d_in[3];
  const float* enc_w1 = (const float*)d_in[4];
  const float* enc_b1 = (const float*)d_in[5];
  const float* enc_w2 = (const float*)d_in[6];
  const float* enc_b2 = (const float*)d_in[7];
  const float* gcn1_w = (const float*)d_in[8];   // gcn1_b [9] cancels in BN
  const float* bn1_g = (const float*)d_in[10];
  const float* bn1_b = (const float*)d_in[11];
  const float* gat_w  = (const float*)d_in[12];
  const float* gat_as = (const float*)d_in[13];
  const float* gat_ad = (const float*)d_in[14];  // gat_b [15] cancels in BN
  const float* bn2_g = (const float*)d_in[16];
  const float* bn2_b = (const float*)d_in[17];
  const float* gcn2_w = (const float*)d_in[18];  // gcn2_b [19] cancels in BN
  const float* bn3_g = (const float*)d_in[20];
  const float* bn3_b = (const float*)d_in[21];
  const float* pw1 = (const float*)d_in[22];
  const float* pb1 = (const float*)d_in[23];
  const float* pw2 = (const float*)d_in[24];
  const float* pb2 = (const float*)d_in[25];
  float* out = (float*)d_out;

  int N = in_sizes[0] / F_IN;
  int E = in_sizes[1] / 2;
  int nbuk = (N + (1 << BSH) - 1) >> BSH;

  const int NBLK_BN = 512;

  char* p = (char*)d_ws;
  auto alloc = [&](size_t bytes) { char* r = p; p += (bytes + 255) & ~(size_t)255; return (void*)r; };
  float* h     = (float*)alloc((size_t)N * 64 * 4);  // encoder out / GAT out; pairs alias
  unsigned short* xw = (unsigned short*)alloc((size_t)N * 64 * 2);  // bf16 gather target
  float* agg   = (float*)alloc((size_t)N * 64 * 4);
  float* as_   = (float*)alloc((size_t)N * 2 * 4);
  float* ad_   = (float*)alloc((size_t)N * 2 * 4);
  float* dinv  = (float*)alloc((size_t)N * 4);
  float* stats = (float*)alloc(2 * 64 * 4);
  float* parts = (float*)alloc((size_t)NBLK_BN * 2 * 64 * 4);
  float* w1g   = (float*)alloc((size_t)F_IN * HID * 4);
  float* c1    = (float*)alloc(HID * 4);
  float* cb    = (float*)alloc(HID * 4);
  int* ideg    = (int*)alloc((size_t)N * 4);
  int* rowst   = (int*)alloc((size_t)N * 4);
  int* csr     = (int*)alloc((size_t)(N + E) * 4);
  int* bukcnt  = (int*)alloc((size_t)MAXBUK * 4);
  int* bukbase = (int*)alloc((size_t)(MAXBUK + 1) * 4);
  int* bukcur  = (int*)alloc((size_t)MAXBUK * 4);
  int* bsum    = (int*)alloc((size_t)MAXBUK * 4);
  int2* pairs  = (int2*)h;  // E*8 bytes <= N*64*4; dead before k_enc writes h

  hipMemsetAsync(bukcnt, 0, (size_t)nbuk * 4, stream);
  hipMemsetAsync(bukcur, 0, (size_t)nbuk * 4, stream);

  int EB = (E + EPB - 1) / EPB;
  int SB = (N + SPB - 1) / SPB;
  int NB = (N + 255) / 256;
  int NB4 = (N + 3) / 4;
  int NB8 = (N + 7) / 8;

  // ---- CSR build (bucketed counting sort; no random global atomics) ----
  k_buk_count<<<EB, 256, 0, stream>>>(ei, bukcnt, E, nbuk);
  k_buk_scan<<<1, 256, 0, stream>>>(bukcnt, bukbase, nbuk);
  k_buk_scatter<<<EB, 256, 0, stream>>>(ei, bukbase, bukcur, pairs, E, nbuk);
  k_buk_deg<<<nbuk, 256, 0, stream>>>(pairs, bukbase, ideg, N);
  k_scan_sums<<<SB, 256, 0, stream>>>(ideg, bsum, N);
  k_scan_tops<<<1, 256, 0, stream>>>(bsum, SB);
  k_scan_apply<<<SB, 256, 0, stream>>>(ideg, bsum, rowst, dinv, csr, N);
  k_buk_fill<<<nbuk, 256, 0, stream>>>(pairs, bukbase, rowst, csr);

  // ---- dense encoder ----
  k_precomp<<<1, 64, 0, stream>>>(enc_w1, ln_g, ln_b, enc_b1, w1g, c1, cb);
  k_enc<<<NB, 256, 0, stream>>>(x_in, w1g, c1, cb, enc_w2, enc_b2, h, N);

  // --- GCN layer 1 ---
  k_gemm_reg<64, false, false><<<NB, 256, 0, stream>>>(h, gcn1_w, nullptr, nullptr, nullptr,
                                                       xw, nullptr, nullptr, N);
  k_gcn_pull64<<<NB4, 256, 0, stream>>>(csr, rowst, ideg, dinv, xw, agg, N);
  k_bn_reduce<64><<<NBLK_BN, 256, 0, stream>>>(agg, parts, N);
  k_bn_finalize<64><<<1, 1024, 0, stream>>>(parts, NBLK_BN, stats, bn1_g, bn1_b, N);

  // --- GAT layer (BN1+ReLU fused into input read; attn+PV fused, online softmax) ---
  k_gemm_reg<64, true, true><<<NB, 256, 0, stream>>>(agg, gat_w, stats, gat_as, gat_ad,
                                                     xw, as_, ad_, N);
  k_gat_fused<<<NB4, 256, 0, stream>>>(csr, rowst, ideg, as_, ad_, xw, h, N);
  k_bn_reduce<64><<<NBLK_BN, 256, 0, stream>>>(h, parts, N);
  k_bn_finalize<64><<<1, 1024, 0, stream>>>(parts, NBLK_BN, stats, bn2_g, bn2_b, N);

  // --- GCN layer 2 (64 -> 32, BN2+ReLU fused into input read) ---
  k_gemm_reg<32, false, true><<<NB, 256, 0, stream>>>(h, gcn2_w, stats, nullptr, nullptr,
                                                      xw, nullptr, nullptr, N);
  k_gcn_pull32<<<NB8, 256, 0, stream>>>(csr, rowst, ideg, dinv, xw, agg, N);
  k_bn_reduce<32><<<NBLK_BN, 256, 0, stream>>>(agg, parts, N);
  k_bn_finalize<32><<<1, 1024, 0, stream>>>(parts, NBLK_BN, stats, bn3_g, bn3_b, N);

  // --- prediction head (BN3+ReLU fused) ---
  k_pred<<<NB, 256, 0, stream>>>(agg, stats, pw1, pb1, pw2, pb2, out, N);
}

// Round 16
// 536.752 us; speedup vs baseline: 1.0635x; 1.0635x over previous
//
#include <hip/hip_runtime.h>
#include <math.h>

#define F_IN 128
#define HID  64
#define EPS  1e-5f
#define NSLOPE 0.2f
#define BSH 9            // bucket = 512 consecutive dst nodes
#define MAXBUK 1024      // supports N <= 512K
#define EPB 4096         // edges per block in bucket passes
#define SPB 4096         // elements per block in scan

__device__ __forceinline__ float lrelu(float x) { return x > 0.f ? x : NSLOPE * x; }

// bf16 pack/unpack (RNE). Gather targets are stored bf16 to halve L2-miss bytes.
__device__ __forceinline__ unsigned short f2bf(float f) {
  unsigned u = __float_as_uint(f);
  return (unsigned short)((u + 0x7FFF + ((u >> 16) & 1)) >> 16);
}
__device__ __forceinline__ float bf2f(unsigned short b) {
  return __uint_as_float((unsigned)b << 16);
}

// ================================================================ CSR build
__global__ __launch_bounds__(256) void k_buk_count(const int* __restrict__ ei,
                                                   int* __restrict__ bukcnt, int E, int nbuk) {
  __shared__ int lc[MAXBUK];
  for (int k = threadIdx.x; k < nbuk; k += 256) lc[k] = 0;
  __syncthreads();
  int base = blockIdx.x * EPB, end = min(E, base + EPB);
  for (int t = base + threadIdx.x; t < end; t += 256) atomicAdd(&lc[ei[E + t] >> BSH], 1);
  __syncthreads();
  for (int k = threadIdx.x; k < nbuk; k += 256)
    if (lc[k]) atomicAdd(&bukcnt[k], lc[k]);
}

__global__ void k_buk_scan(const int* __restrict__ bukcnt, int* __restrict__ bukbase, int nbuk) {
  __shared__ int l[MAXBUK + 1];
  for (int k = threadIdx.x; k < nbuk; k += blockDim.x) l[k] = bukcnt[k];
  __syncthreads();
  if (threadIdx.x == 0) {
    int r = 0;
    for (int k = 0; k < nbuk; ++k) { int t = l[k]; l[k] = r; r += t; }
    l[nbuk] = r;
  }
  __syncthreads();
  for (int k = threadIdx.x; k <= nbuk; k += blockDim.x) bukbase[k] = l[k];
}

__global__ __launch_bounds__(256) void k_buk_scatter(const int* __restrict__ ei,
                                                     const int* __restrict__ bukbase,
                                                     int* __restrict__ bukcur,
                                                     int2* __restrict__ pairs, int E, int nbuk) {
  __shared__ int lc[MAXBUK];
  __shared__ int lbase[MAXBUK];
  for (int k = threadIdx.x; k < nbuk; k += 256) lc[k] = 0;
  __syncthreads();
  int base = blockIdx.x * EPB, end = min(E, base + EPB);
  for (int t = base + threadIdx.x; t < end; t += 256) atomicAdd(&lc[ei[E + t] >> BSH], 1);
  __syncthreads();
  for (int k = threadIdx.x; k < nbuk; k += 256) {
    int c = lc[k];
    lbase[k] = c ? atomicAdd(&bukcur[k], c) : 0;
  }
  __syncthreads();
  for (int k = threadIdx.x; k < nbuk; k += 256) lc[k] = 0;
  __syncthreads();
  for (int t = base + threadIdx.x; t < end; t += 256) {
    int s = ei[t], d = ei[E + t];
    int b = d >> BSH;
    int o = atomicAdd(&lc[b], 1);
    pairs[bukbase[b] + lbase[b] + o] = make_int2(s, d);
  }
}

__global__ __launch_bounds__(256) void k_buk_deg(const int2* __restrict__ pairs,
                                                 const int* __restrict__ bukbase,
                                                 int* __restrict__ ideg, int N) {
  __shared__ int ldeg[1 << BSH];
  int b = blockIdx.x;
  for (int k = threadIdx.x; k < (1 << BSH); k += 256) ldeg[k] = 0;
  __syncthreads();
  int s0 = bukbase[b], s1 = bukbase[b + 1], nb = b << BSH;
  for (int t = s0 + threadIdx.x; t < s1; t += 256) atomicAdd(&ldeg[pairs[t].y - nb], 1);
  __syncthreads();
  for (int k = threadIdx.x; k < (1 << BSH); k += 256) {
    int node = nb + k;
    if (node < N) ideg[node] = ldeg[k];
  }
}

__global__ __launch_bounds__(256) void k_scan_sums(const int* __restrict__ ideg,
                                                   int* __restrict__ bsum, int N) {
  __shared__ int red[256];
  int base = blockIdx.x * SPB + threadIdx.x * 16;
  int s = 0;
#pragma unroll
  for (int j = 0; j < 16; ++j) { int i = base + j; if (i < N) s += ideg[i] + 1; }
  red[threadIdx.x] = s;
  __syncthreads();
  for (int o = 128; o; o >>= 1) {
    if (threadIdx.x < o) red[threadIdx.x] += red[threadIdx.x + o];
    __syncthreads();
  }
  if (threadIdx.x == 0) bsum[blockIdx.x] = red[0];
}

__global__ void k_scan_tops(int* __restrict__ bsum, int nb) {
  __shared__ int l[MAXBUK];
  for (int k = threadIdx.x; k < nb; k += blockDim.x) l[k] = bsum[k];
  __syncthreads();
  if (threadIdx.x == 0) {
    int r = 0;
    for (int k = 0; k < nb; ++k) { int t = l[k]; l[k] = r; r += t; }
  }
  __syncthreads();
  for (int k = threadIdx.x; k < nb; k += blockDim.x) bsum[k] = l[k];
}

__global__ __launch_bounds__(256) void k_scan_apply(const int* __restrict__ ideg,
                                                    const int* __restrict__ bsum,
                                                    int* __restrict__ rowstart,
                                                    float* __restrict__ dinv,
                                                    int* __restrict__ csr, int N) {
  __shared__ int pre[256];
  int base = blockIdx.x * SPB + threadIdx.x * 16;
  int deg[16];
  int s = 0;
#pragma unroll
  for (int j = 0; j < 16; ++j) {
    int i = base + j;
    int d = (i < N) ? ideg[i] + 1 : 0;
    deg[j] = d; s += d;
  }
  pre[threadIdx.x] = s;
  __syncthreads();
  for (int o = 1; o < 256; o <<= 1) {
    int v = (threadIdx.x >= o) ? pre[threadIdx.x - o] : 0;
    __syncthreads();
    pre[threadIdx.x] += v;
    __syncthreads();
  }
  int off = bsum[blockIdx.x] + pre[threadIdx.x] - s;
#pragma unroll
  for (int j = 0; j < 16; ++j) {
    int i = base + j;
    if (i < N) {
      rowstart[i] = off;
      dinv[i] = rsqrtf((float)deg[j]);
      csr[off] = i;               // self-loop at slot 0
      off += deg[j];
    }
  }
}

__global__ __launch_bounds__(256) void k_buk_fill(const int2* __restrict__ pairs,
                                                  const int* __restrict__ bukbase,
                                                  const int* __restrict__ rowstart,
                                                  int* __restrict__ csr) {
  __shared__ int lcur[1 << BSH];
  int b = blockIdx.x;
  for (int k = threadIdx.x; k < (1 << BSH); k += 256) lcur[k] = 0;
  __syncthreads();
  int s0 = bukbase[b], s1 = bukbase[b + 1], nb = b << BSH;
  for (int t = s0 + threadIdx.x; t < s1; t += 256) {
    int2 pr = pairs[t];
    int o = atomicAdd(&lcur[pr.y - nb], 1);
    csr[rowstart[pr.y] + 1 + o] = pr.x;
  }
}

// ------------------------------------------------- precompute LN-folded weights
__global__ void k_precomp(const float* __restrict__ w1, const float* __restrict__ ln_g,
                          const float* __restrict__ ln_b, const float* __restrict__ b1,
                          float* __restrict__ w1g, float* __restrict__ c1,
                          float* __restrict__ cb) {
  int j = threadIdx.x;  // 64 threads
  float c1v = 0.f, cbv = 0.f;
  for (int k = 0; k < F_IN; ++k) {
    float w = w1[k * HID + j];
    float wg = ln_g[k] * w;
    w1g[k * HID + j] = wg;
    c1v += wg;
    cbv += ln_b[k] * w;
  }
  c1[j] = c1v;
  cb[j] = cbv + b1[j];
}

// -------------------- Encoder: LN (folded) + GEMM1 + ReLU + GEMM2 + ReLU
// thread=node, lane-uniform weight addresses -> scalar loads. unroll 1 on the
// hot loop is deliberate: wider unroll regressed (round-15, I-cache/scheduling).
__global__ __launch_bounds__(256) void k_enc(
    const float* __restrict__ x, const float* __restrict__ w1g,
    const float* __restrict__ c1, const float* __restrict__ cb,
    const float* __restrict__ w2, const float* __restrict__ b2,
    float* __restrict__ out, int N) {
  __shared__ float shl[256 * 65];
  int i = blockIdx.x * 256 + threadIdx.x;
  if (i >= N) return;
  const float4* xr = (const float4*)(x + (size_t)i * F_IN);
  float acc[HID];
#pragma unroll
  for (int j = 0; j < HID; ++j) acc[j] = 0.f;
  float s = 0.f, q = 0.f;
#pragma unroll 1
  for (int c = 0; c < F_IN / 4; ++c) {
    float4 xv = xr[c];
    s += xv.x + xv.y + xv.z + xv.w;
    q += xv.x * xv.x + xv.y * xv.y + xv.z * xv.z + xv.w * xv.w;
    const float* wr = w1g + c * 4 * HID;
#pragma unroll
    for (int e = 0; e < 4; ++e) {
      float xe = (e == 0) ? xv.x : (e == 1) ? xv.y : (e == 2) ? xv.z : xv.w;
      const float4* w4 = (const float4*)(wr + e * HID);
#pragma unroll
      for (int j4 = 0; j4 < HID / 4; ++j4) {
        float4 wv = w4[j4];
        acc[j4 * 4 + 0] += xe * wv.x;
        acc[j4 * 4 + 1] += xe * wv.y;
        acc[j4 * 4 + 2] += xe * wv.z;
        acc[j4 * 4 + 3] += xe * wv.w;
      }
    }
  }
  float mu = s * (1.f / F_IN);
  float var = q * (1.f / F_IN) - mu * mu;
  float rs = rsqrtf(var + EPS);
  int base = threadIdx.x * 65;
#pragma unroll
  for (int j = 0; j < HID; ++j)
    shl[base + j] = fmaxf(rs * (acc[j] - mu * c1[j]) + cb[j], 0.f);
  float acc2[HID];
#pragma unroll
  for (int j = 0; j < HID; ++j) acc2[j] = b2[j];
#pragma unroll 4
  for (int j = 0; j < HID; ++j) {
    float hj = shl[base + j];
    const float4* w4 = (const float4*)(w2 + j * HID);
#pragma unroll
    for (int c4 = 0; c4 < HID / 4; ++c4) {
      float4 wv = w4[c4];
      acc2[c4 * 4 + 0] += hj * wv.x;
      acc2[c4 * 4 + 1] += hj * wv.y;
      acc2[c4 * 4 + 2] += hj * wv.z;
      acc2[c4 * 4 + 3] += hj * wv.w;
    }
  }
  float4* o4 = (float4*)(out + (size_t)i * HID);
#pragma unroll
  for (int c4 = 0; c4 < HID / 4; ++c4)
    o4[c4] = make_float4(fmaxf(acc2[c4 * 4 + 0], 0.f), fmaxf(acc2[c4 * 4 + 1], 0.f),
                         fmaxf(acc2[c4 * 4 + 2], 0.f), fmaxf(acc2[c4 * 4 + 3], 0.f));
}

// -------------------- [N,64] @ [64,FOUT], thread=node, scalar weights, bf16 out.
template <int FOUT, bool GAT, bool BNIN>
__global__ __launch_bounds__(256) void k_gemm_reg(
    const float* __restrict__ x, const float* __restrict__ w,
    const float* __restrict__ stats,
    const float* __restrict__ atts, const float* __restrict__ atd,
    unsigned short* __restrict__ out, float* __restrict__ a_s, float* __restrict__ a_d, int N) {
  int i = blockIdx.x * 256 + threadIdx.x;
  if (i >= N) return;
  const float4* xr = (const float4*)(x + (size_t)i * HID);
  float acc[FOUT];
#pragma unroll
  for (int j = 0; j < FOUT; ++j) acc[j] = 0.f;
#pragma unroll 1
  for (int c = 0; c < HID / 4; ++c) {
    float4 xv = xr[c];
    if (BNIN) {
      xv.x = fmaxf(xv.x * stats[c * 4 + 0] + stats[HID + c * 4 + 0], 0.f);
      xv.y = fmaxf(xv.y * stats[c * 4 + 1] + stats[HID + c * 4 + 1], 0.f);
      xv.z = fmaxf(xv.z * stats[c * 4 + 2] + stats[HID + c * 4 + 2], 0.f);
      xv.w = fmaxf(xv.w * stats[c * 4 + 3] + stats[HID + c * 4 + 3], 0.f);
    }
    const float* wr = w + c * 4 * FOUT;
#pragma unroll
    for (int e = 0; e < 4; ++e) {
      float xe = (e == 0) ? xv.x : (e == 1) ? xv.y : (e == 2) ? xv.z : xv.w;
      const float4* w4 = (const float4*)(wr + e * FOUT);
#pragma unroll
      for (int j4 = 0; j4 < FOUT / 4; ++j4) {
        float4 wv = w4[j4];
        acc[j4 * 4 + 0] += xe * wv.x;
        acc[j4 * 4 + 1] += xe * wv.y;
        acc[j4 * 4 + 2] += xe * wv.z;
        acc[j4 * 4 + 3] += xe * wv.w;
      }
    }
  }
  unsigned short* orow = out + (size_t)i * FOUT;
#pragma unroll
  for (int j8 = 0; j8 < FOUT / 8; ++j8) {
    uint4 pk;
    pk.x = ((unsigned)f2bf(acc[j8 * 8 + 1]) << 16) | f2bf(acc[j8 * 8 + 0]);
    pk.y = ((unsigned)f2bf(acc[j8 * 8 + 3]) << 16) | f2bf(acc[j8 * 8 + 2]);
    pk.z = ((unsigned)f2bf(acc[j8 * 8 + 5]) << 16) | f2bf(acc[j8 * 8 + 4]);
    pk.w = ((unsigned)f2bf(acc[j8 * 8 + 7]) << 16) | f2bf(acc[j8 * 8 + 6]);
    *(uint4*)(orow + j8 * 8) = pk;
  }
  if (GAT) {
    float s0 = 0.f, s1 = 0.f, d0 = 0.f, d1 = 0.f;
#pragma unroll
    for (int c = 0; c < 32; ++c) { s0 += acc[c] * atts[c]; d0 += acc[c] * atd[c]; }
#pragma unroll
    for (int c = 32; c < 64; ++c) { s1 += acc[c] * atts[c]; d1 += acc[c] * atd[c]; }
    a_s[i * 2] = s0; a_s[i * 2 + 1] = s1;
    a_d[i * 2] = d0; a_d[i * 2 + 1] = d1;
  }
}

// ---------------------------------------------------- GCN pull F=64 (wave per node)
__global__ __launch_bounds__(256) void k_gcn_pull64(
    const int* __restrict__ csr, const int* __restrict__ rowstart, const int* __restrict__ ideg,
    const float* __restrict__ dinv, const unsigned short* __restrict__ xw,
    float* __restrict__ out, int N) {
  int wave = threadIdx.x >> 6, lane = threadIdx.x & 63;
  int i = blockIdx.x * 4 + wave;
  if (i >= N) return;
  int row = rowstart[i], dg = ideg[i] + 1;
  float did = dinv[i];
  float acc = 0.f;
  for (int base = 0; base < dg; base += 64) {
    int cnt = min(64, dg - base);
    int sid = (lane < cnt) ? csr[row + base + lane] : 0;
    int n = 0;
    for (; n + 4 <= cnt; n += 4) {
      int s0 = __shfl(sid, n), s1 = __shfl(sid, n + 1);
      int s2 = __shfl(sid, n + 2), s3 = __shfl(sid, n + 3);
      acc += dinv[s0] * did * bf2f(xw[s0 * 64 + lane]) + dinv[s1] * did * bf2f(xw[s1 * 64 + lane]) +
             dinv[s2] * did * bf2f(xw[s2 * 64 + lane]) + dinv[s3] * did * bf2f(xw[s3 * 64 + lane]);
    }
    for (; n < cnt; ++n) {
      int s0 = __shfl(sid, n);
      acc += dinv[s0] * did * bf2f(xw[s0 * 64 + lane]);
    }
  }
  out[i * 64 + lane] = acc;
}

// ---------------------------------------------------- GCN pull F=32 (2 nodes per wave)
__global__ __launch_bounds__(256) void k_gcn_pull32(
    const int* __restrict__ csr, const int* __restrict__ rowstart, const int* __restrict__ ideg,
    const float* __restrict__ dinv, const unsigned short* __restrict__ xw,
    float* __restrict__ out, int N) {
  int wave = threadIdx.x >> 6, lane = threadIdx.x & 63;
  int half = lane >> 5, lf = lane & 31;
  int i = (blockIdx.x * 4 + wave) * 2 + half;
  if (i >= N) return;
  int row = rowstart[i], dg = ideg[i] + 1;
  float did = dinv[i];
  float acc = 0.f;
  for (int base = 0; base < dg; base += 32) {
    int cnt = min(32, dg - base);
    int sid = (lf < cnt) ? csr[row + base + lf] : 0;
    int n = 0;
    for (; n + 2 <= cnt; n += 2) {
      int s0 = __shfl(sid, n, 32), s1 = __shfl(sid, n + 1, 32);
      acc += dinv[s0] * did * bf2f(xw[s0 * 32 + lf]) + dinv[s1] * did * bf2f(xw[s1 * 32 + lf]);
    }
    for (; n < cnt; ++n) {
      int s0 = __shfl(sid, n, 32);
      acc += dinv[s0] * did * bf2f(xw[s0 * 32 + lf]);
    }
  }
  out[i * 32 + lf] = acc;
}

// -------------------- GAT fused: online-softmax + PV, half-wave heads.
// Both 32-lane halves process the SAME 32 neighbors; half h = lane>>5 owns head h.
// All shuffles convergent (round-12 lesson).
__global__ __launch_bounds__(256) void k_gat_fused(
    const int* __restrict__ csr, const int* __restrict__ rowstart, const int* __restrict__ ideg,
    const float* __restrict__ a_s, const float* __restrict__ a_d,
    const unsigned short* __restrict__ xw, float* __restrict__ out, int N) {
  int wave = threadIdx.x >> 6, lane = threadIdx.x & 63;
  int i = blockIdx.x * 4 + wave;
  if (i >= N) return;
  int h = lane >> 5, lf = lane & 31;
  int row = rowstart[i], dg = ideg[i] + 1;
  float adh = a_d[i * 2 + h];
  float m = -1e30f, z = 0.f, accA = 0.f, accB = 0.f;
  for (int base = 0; base < dg; base += 32) {
    int cnt = min(32, dg - base);
    int sid = (lf < cnt) ? csr[row + base + lf] : 0;   // lanes l and l+32 hold same sid
    float e = -1e30f;
    if (lf < cnt) e = lrelu(a_s[sid * 2 + h] + adh);
    float cm = e;
#pragma unroll
    for (int o = 16; o; o >>= 1) cm = fmaxf(cm, __shfl_xor(cm, o));
    float nm = fmaxf(m, cm);
    float r = __expf(m - nm);          // first chunk: exp(-inf)=0 zeroes z/acc
    z *= r; accA *= r; accB *= r;
    m = nm;
    float p = (lf < cnt) ? __expf(e - m) : 0.f;
    float sz = p;
#pragma unroll
    for (int o = 16; o; o >>= 1) sz += __shfl_xor(sz, o);
    z += sz;
    int hb = h << 5;
    int n = 0;
    for (; n + 2 <= cnt; n += 2) {
      int v0 = __shfl(sid, n), v1 = __shfl(sid, n + 1);
      float al0 = __shfl(p, hb + n);
      float al1 = __shfl(p, hb + n + 1);
      accA += al0 * bf2f(xw[v0 * HID + lane]);
      accB += al1 * bf2f(xw[v1 * HID + lane]);
    }
    for (; n < cnt; ++n) {
      int v0 = __shfl(sid, n);
      float al0 = __shfl(p, hb + n);
      accA += al0 * bf2f(xw[v0 * HID + lane]);
    }
  }
  out[i * HID + lane] = (accA + accB) / (z + 1e-16f);
}

// ------------------------------ BatchNorm stats: block partials, no global atomics
template <int F>
__global__ __launch_bounds__(256) void k_bn_reduce(const float* __restrict__ x,
                                                   float* __restrict__ partials, int N) {
  __shared__ float sS[F], sQ[F];
  int tid = threadIdx.x;
  int t = blockIdx.x * 256 + tid;
  int stride = gridDim.x * 256;
  int total4 = N * F / 4;
  int f0 = (t * 4) % F;
  float s0 = 0, s1 = 0, s2 = 0, s3 = 0, q0 = 0, q1 = 0, q2 = 0, q3 = 0;
  for (int c = t; c < total4; c += stride) {
    float4 v = ((const float4*)x)[c];
    s0 += v.x; q0 += v.x * v.x;
    s1 += v.y; q1 += v.y * v.y;
    s2 += v.z; q2 += v.z * v.z;
    s3 += v.w; q3 += v.w * v.w;
  }
  if (tid < F) { sS[tid] = 0.f; sQ[tid] = 0.f; }
  __syncthreads();
  atomicAdd(&sS[f0], s0);     atomicAdd(&sQ[f0], q0);
  atomicAdd(&sS[f0 + 1], s1); atomicAdd(&sQ[f0 + 1], q1);
  atomicAdd(&sS[f0 + 2], s2); atomicAdd(&sQ[f0 + 2], q2);
  atomicAdd(&sS[f0 + 3], s3); atomicAdd(&sQ[f0 + 3], q3);
  __syncthreads();
  if (tid < F) {
    partials[blockIdx.x * 2 * F + tid]     = sS[tid];
    partials[blockIdx.x * 2 * F + F + tid] = sQ[tid];
  }
}

// 1024-thread parallel finalize
template <int F>
__global__ __launch_bounds__(1024) void k_bn_finalize(
    const float* __restrict__ partials, int nblk,
    float* __restrict__ stats, const float* __restrict__ g,
    const float* __restrict__ b, int N) {
  const int TF = 2 * F;
  const int NGRP = 1024 / TF;
  __shared__ float sh[1024];
  int tid = threadIdx.x;
  int f = tid % TF;
  int grp = tid / TF;
  float s = 0.f;
  for (int k = grp; k < nblk; k += NGRP) s += partials[(size_t)k * TF + f];
  sh[tid] = s;
  __syncthreads();
  for (int off = NGRP / 2; off > 0; off >>= 1) {
    if (grp < off) sh[tid] += sh[tid + off * TF];
    __syncthreads();
  }
  if (tid < F) {
    float S = sh[tid], Q = sh[F + tid];
    float mu = S / (float)N;
    float var = Q / (float)N - mu * mu;
    float sc = rsqrtf(var + EPS) * g[tid];
    stats[tid] = sc;
    stats[F + tid] = b[tid] - mu * sc;
  }
}

// ---------------------------------------------------- prediction head (BN3 fused)
__global__ __launch_bounds__(256) void k_pred(
    const float* __restrict__ x, const float* __restrict__ stats,
    const float* __restrict__ w1, const float* __restrict__ b1,
    const float* __restrict__ w2, const float* __restrict__ b2,
    float* __restrict__ out, int N) {
  int i = blockIdx.x * 256 + threadIdx.x;
  if (i >= N) return;
  const float4* xr = (const float4*)(x + (size_t)i * 32);
  float acc[16];
#pragma unroll
  for (int j = 0; j < 16; ++j) acc[j] = b1[j];
#pragma unroll 1
  for (int c = 0; c < 8; ++c) {
    float4 xv = xr[c];
    xv.x = fmaxf(xv.x * stats[c * 4 + 0] + stats[32 + c * 4 + 0], 0.f);
    xv.y = fmaxf(xv.y * stats[c * 4 + 1] + stats[32 + c * 4 + 1], 0.f);
    xv.z = fmaxf(xv.z * stats[c * 4 + 2] + stats[32 + c * 4 + 2], 0.f);
    xv.w = fmaxf(xv.w * stats[c * 4 + 3] + stats[32 + c * 4 + 3], 0.f);
    const float* wr = w1 + c * 4 * 16;
#pragma unroll
    for (int e = 0; e < 4; ++e) {
      float xe = (e == 0) ? xv.x : (e == 1) ? xv.y : (e == 2) ? xv.z : xv.w;
      const float4* w4 = (const float4*)(wr + e * 16);
#pragma unroll
      for (int j4 = 0; j4 < 4; ++j4) {
        float4 wv = w4[j4];
        acc[j4 * 4 + 0] += xe * wv.x;
        acc[j4 * 4 + 1] += xe * wv.y;
        acc[j4 * 4 + 2] += xe * wv.z;
        acc[j4 * 4 + 3] += xe * wv.w;
      }
    }
  }
  float z = b2[0];
#pragma unroll
  for (int j = 0; j < 16; ++j) z += fmaxf(acc[j], 0.f) * w2[j];
  out[i] = 1.f / (1.f + __expf(-z));
}

// ================================================================ launch
extern "C" void kernel_launch(void* const* d_in, const int* in_sizes, int n_in,
                              void* d_out, int out_size, void* d_ws, size_t ws_size,
                              hipStream_t stream) {
  const float* x_in  = (const float*)d_in[0];
  const int*   ei    = (const int*)d_in[1];
  const float* ln_g  = (const float*)d_in[2];
  const float* ln_b  = (const float*)d_in[3];
  const float* enc_w1 = (const float*)d_in[4];
  const float* enc_b1 = (const float*)d_in[5];
  const float* enc_w2 = (const float*)d_in[6];
  const float* enc_b2 = (const float*)d_in[7];
  const float* gcn1_w = (const float*)d_in[8];   // gcn1_b [9] cancels in BN
  const float* bn1_g = (const float*)d_in[10];
  const float* bn1_b = (const float*)d_in[11];
  const float* gat_w  = (const float*)d_in[12];
  const float* gat_as = (const float*)d_in[13];
  const float* gat_ad = (const float*)d_in[14];  // gat_b [15] cancels in BN
  const float* bn2_g = (const float*)d_in[16];
  const float* bn2_b = (const float*)d_in[17];
  const float* gcn2_w = (const float*)d_in[18];  // gcn2_b [19] cancels in BN
  const float* bn3_g = (const float*)d_in[20];
  const float* bn3_b = (const float*)d_in[21];
  const float* pw1 = (const float*)d_in[22];
  const float* pb1 = (const float*)d_in[23];
  const float* pw2 = (const float*)d_in[24];
  const float* pb2 = (const float*)d_in[25];
  float* out = (float*)d_out;

  int N = in_sizes[0] / F_IN;
  int E = in_sizes[1] / 2;
  int nbuk = (N + (1 << BSH) - 1) >> BSH;

  const int NBLK_BN = 512;

  char* p = (char*)d_ws;
  auto alloc = [&](size_t bytes) { char* r = p; p += (bytes + 255) & ~(size_t)255; return (void*)r; };
  float* h     = (float*)alloc((size_t)N * 64 * 4);  // encoder out / GAT out; pairs alias
  unsigned short* xw = (unsigned short*)alloc((size_t)N * 64 * 2);  // bf16 gather target
  float* agg   = (float*)alloc((size_t)N * 64 * 4);
  float* as_   = (float*)alloc((size_t)N * 2 * 4);
  float* ad_   = (float*)alloc((size_t)N * 2 * 4);
  float* dinv  = (float*)alloc((size_t)N * 4);
  float* stats = (float*)alloc(2 * 64 * 4);
  float* parts = (float*)alloc((size_t)NBLK_BN * 2 * 64 * 4);
  float* w1g   = (float*)alloc((size_t)F_IN * HID * 4);
  float* c1    = (float*)alloc(HID * 4);
  float* cb    = (float*)alloc(HID * 4);
  int* ideg    = (int*)alloc((size_t)N * 4);
  int* rowst   = (int*)alloc((size_t)N * 4);
  int* csr     = (int*)alloc((size_t)(N + E) * 4);
  int* bukcnt  = (int*)alloc((size_t)MAXBUK * 4);
  int* bukbase = (int*)alloc((size_t)(MAXBUK + 1) * 4);
  int* bukcur  = (int*)alloc((size_t)MAXBUK * 4);
  int* bsum    = (int*)alloc((size_t)MAXBUK * 4);
  int2* pairs  = (int2*)h;  // E*8 bytes <= N*64*4; dead before k_enc writes h

  hipMemsetAsync(bukcnt, 0, (size_t)nbuk * 4, stream);
  hipMemsetAsync(bukcur, 0, (size_t)nbuk * 4, stream);

  int EB = (E + EPB - 1) / EPB;
  int SB = (N + SPB - 1) / SPB;
  int NB = (N + 255) / 256;
  int NB4 = (N + 3) / 4;
  int NB8 = (N + 7) / 8;

  // ---- CSR build (bucketed counting sort; no random global atomics) ----
  k_buk_count<<<EB, 256, 0, stream>>>(ei, bukcnt, E, nbuk);
  k_buk_scan<<<1, 256, 0, stream>>>(bukcnt, bukbase, nbuk);
  k_buk_scatter<<<EB, 256, 0, stream>>>(ei, bukbase, bukcur, pairs, E, nbuk);
  k_buk_deg<<<nbuk, 256, 0, stream>>>(pairs, bukbase, ideg, N);
  k_scan_sums<<<SB, 256, 0, stream>>>(ideg, bsum, N);
  k_scan_tops<<<1, 256, 0, stream>>>(bsum, SB);
  k_scan_apply<<<SB, 256, 0, stream>>>(ideg, bsum, rowst, dinv, csr, N);
  k_buk_fill<<<nbuk, 256, 0, stream>>>(pairs, bukbase, rowst, csr);

  // ---- dense encoder ----
  k_precomp<<<1, 64, 0, stream>>>(enc_w1, ln_g, ln_b, enc_b1, w1g, c1, cb);
  k_enc<<<NB, 256, 0, stream>>>(x_in, w1g, c1, cb, enc_w2, enc_b2, h, N);

  // --- GCN layer 1 ---
  k_gemm_reg<64, false, false><<<NB, 256, 0, stream>>>(h, gcn1_w, nullptr, nullptr, nullptr,
                                                       xw, nullptr, nullptr, N);
  k_gcn_pull64<<<NB4, 256, 0, stream>>>(csr, rowst, ideg, dinv, xw, agg, N);
  k_bn_reduce<64><<<NBLK_BN, 256, 0, stream>>>(agg, parts, N);
  k_bn_finalize<64><<<1, 1024, 0, stream>>>(parts, NBLK_BN, stats, bn1_g, bn1_b, N);

  // --- GAT layer (BN1+ReLU fused into input read; attn+PV fused, online softmax) ---
  k_gemm_reg<64, true, true><<<NB, 256, 0, stream>>>(agg, gat_w, stats, gat_as, gat_ad,
                                                     xw, as_, ad_, N);
  k_gat_fused<<<NB4, 256, 0, stream>>>(csr, rowst, ideg, as_, ad_, xw, h, N);
  k_bn_reduce<64><<<NBLK_BN, 256, 0, stream>>>(h, parts, N);
  k_bn_finalize<64><<<1, 1024, 0, stream>>>(parts, NBLK_BN, stats, bn2_g, bn2_b, N);

  // --- GCN layer 2 (64 -> 32, BN2+ReLU fused into input read) ---
  k_gemm_reg<32, false, true><<<NB, 256, 0, stream>>>(h, gcn2_w, stats, nullptr, nullptr,
                                                      xw, nullptr, nullptr, N);
  k_gcn_pull32<<<NB8, 256, 0, stream>>>(csr, rowst, ideg, dinv, xw, agg, N);
  k_bn_reduce<32><<<NBLK_BN, 256, 0, stream>>>(agg, parts, N);
  k_bn_finalize<32><<<1, 1024, 0, stream>>>(parts, NBLK_BN, stats, bn3_g, bn3_b, N);

  // --- prediction head (BN3+ReLU fused) ---
  k_pred<<<NB, 256, 0, stream>>>(agg, stats, pw1, pb1, pw2, pb2, out, N);
}